// Round 1
// baseline (1168.830 us; speedup 1.0000x reference)
//
#include <hip/hip_runtime.h>

#define NEG_SLOPE 0.2f
static constexpr float BN_INV = 0.9999950000374997f; // 1/sqrt(1+1e-5)

// ===================== CSR build =====================
__global__ void hist_kernel(const int* __restrict__ dst, int* __restrict__ cnt, int E){
  int e = blockIdx.x*256 + threadIdx.x;
  if (e < E) atomicAdd(&cnt[dst[e]], 1);
}

__global__ __launch_bounds__(1024) void scan_kernel(int* __restrict__ cnt_cursor, int* __restrict__ offs, int n){
  __shared__ int sdata[1024];
  __shared__ int carry;
  int tid = threadIdx.x;
  if (tid == 0){ carry = 0; offs[0] = 0; }
  __syncthreads();
  for (int base = 0; base < n; base += 1024){
    int i = base + tid;
    int v = (i < n) ? cnt_cursor[i] : 0;
    sdata[tid] = v;
    __syncthreads();
    for (int off = 1; off < 1024; off <<= 1){
      int t = (tid >= off) ? sdata[tid - off] : 0;
      __syncthreads();
      sdata[tid] += t;
      __syncthreads();
    }
    int inc = sdata[tid] + carry;    // inclusive prefix
    if (i < n){ offs[i+1] = inc; cnt_cursor[i] = inc - v; }  // cursor = exclusive start
    __syncthreads();
    if (tid == 1023) carry = inc;
    __syncthreads();
  }
}

__global__ void scatter_kernel(const int* __restrict__ src, const int* __restrict__ dst,
                               int* __restrict__ cursor, int* __restrict__ perm_edge,
                               int* __restrict__ perm_src, int* __restrict__ perm_dst, int E){
  int e = blockIdx.x*256 + threadIdx.x;
  if (e >= E) return;
  int d = dst[e];
  int pos = atomicAdd(&cursor[d], 1);
  perm_edge[pos] = e;
  perm_src[pos]  = src[e];
  perm_dst[pos]  = d;
}

// ===================== fold We @ ae -> M[6][H] =====================
__global__ void foldm_kernel(const float* __restrict__ We, const float* __restrict__ ae,
                             float* __restrict__ M, int H){
  int t = threadIdx.x;
  if (t >= 6*H) return;
  int C = 256 / H;
  int k = t / H, h = t % H;
  float s = 0.f;
  for (int c = 0; c < C; ++c) s += We[k*256 + h*C + c] * ae[h*C + c];
  M[k*H + h] = s;
}

// ===================== generic fp32 GEMM: C = act(bn(A@W + bias)) =====================
// A:[M,K] row-major, W:[K,N] row-major, 64x64 tile, 4x4 per thread, KT=32
template<bool USE_BIAS, bool USE_BN, bool USE_RELU>
__global__ __launch_bounds__(256) void gemm_kernel(
    const float* __restrict__ A, const float* __restrict__ W,
    const float* __restrict__ bias, const float* __restrict__ gam, const float* __restrict__ bet,
    float* __restrict__ C, int M, int N, int K)
{
  __shared__ float As[32][68];   // transposed A tile, padded: row stride 68*4B = 16B-aligned
  __shared__ float Bs[32][64];
  int tid = threadIdx.x;
  int tx = tid & 15, ty = tid >> 4;
  int bn0 = blockIdx.x * 64, bm0 = blockIdx.y * 64;
  float acc[4][4] = {};
  for (int k0 = 0; k0 < K; k0 += 32){
    int kk = tid & 31, mm0 = tid >> 5;
#pragma unroll
    for (int r = 0; r < 8; ++r){
      int ml = mm0 + r*8;
      int m = bm0 + ml;
      As[kk][ml] = (m < M) ? A[(size_t)m*K + k0 + kk] : 0.f;
    }
    int nn = tid & 63, kb = tid >> 6;
#pragma unroll
    for (int r = 0; r < 8; ++r){
      int kl = kb + r*4;
      int n = bn0 + nn;
      Bs[kl][nn] = (n < N) ? W[(size_t)(k0 + kl)*N + n] : 0.f;
    }
    __syncthreads();
#pragma unroll
    for (int k = 0; k < 32; ++k){
      float4 a4 = *reinterpret_cast<const float4*>(&As[k][ty*4]);
      float4 b4 = *reinterpret_cast<const float4*>(&Bs[k][tx*4]);
      acc[0][0] += a4.x*b4.x; acc[0][1] += a4.x*b4.y; acc[0][2] += a4.x*b4.z; acc[0][3] += a4.x*b4.w;
      acc[1][0] += a4.y*b4.x; acc[1][1] += a4.y*b4.y; acc[1][2] += a4.y*b4.z; acc[1][3] += a4.y*b4.w;
      acc[2][0] += a4.z*b4.x; acc[2][1] += a4.z*b4.y; acc[2][2] += a4.z*b4.z; acc[2][3] += a4.z*b4.w;
      acc[3][0] += a4.w*b4.x; acc[3][1] += a4.w*b4.y; acc[3][2] += a4.w*b4.z; acc[3][3] += a4.w*b4.w;
    }
    __syncthreads();
  }
#pragma unroll
  for (int i = 0; i < 4; ++i){
    int m = bm0 + ty*4 + i;
    if (m < M){
#pragma unroll
      for (int j = 0; j < 4; ++j){
        int n = bn0 + tx*4 + j;
        if (n < N){
          float c = acc[i][j];
          if (USE_BIAS) c += bias[n];
          if (USE_BN)   c = gam[n]*c*BN_INV + bet[n];
          if (USE_RELU) c = fmaxf(c, 0.f);
          C[(size_t)m*N + n] = c;
        }
      }
    }
  }
}

// ===================== per-node attention logits al_s/al_d =====================
template<int HH>
__global__ void alsd_kernel(const float* __restrict__ xp, const float* __restrict__ a_s,
                            const float* __restrict__ a_d, float* __restrict__ als,
                            float* __restrict__ ald, int Nn){
  int gid = blockIdx.x*blockDim.x + threadIdx.x;
  int wave = gid >> 6, lane = threadIdx.x & 63;
  if (wave >= Nn) return;
  float4 xv = reinterpret_cast<const float4*>(xp)[(size_t)wave*64 + lane];
  float4 av = reinterpret_cast<const float4*>(a_s)[lane];   // flat [H*C] matches lane*4
  float4 dv = reinterpret_cast<const float4*>(a_d)[lane];
  float ps = xv.x*av.x + xv.y*av.y + xv.z*av.z + xv.w*av.w;
  float pd = xv.x*dv.x + xv.y*dv.y + xv.z*dv.z + xv.w*dv.w;
  if constexpr (HH == 8){
    ps += __shfl_xor(ps,1); pd += __shfl_xor(pd,1);
    ps += __shfl_xor(ps,2); pd += __shfl_xor(pd,2);
    ps += __shfl_xor(ps,4); pd += __shfl_xor(pd,4);
    if ((lane & 7) == 0){
      als[wave*8 + (lane>>3)] = ps;
      ald[wave*8 + (lane>>3)] = pd;
    }
  } else {
#pragma unroll
    for (int off = 1; off < 64; off <<= 1){ ps += __shfl_xor(ps,off); pd += __shfl_xor(pd,off); }
    if (lane == 0){ als[wave] = ps; ald[wave] = pd; }
  }
}

// ===================== per-edge attention logits (sorted order) =====================
template<int HH>
__global__ void alpha_kernel(const int* __restrict__ perm_edge, const int* __restrict__ perm_src,
                             const int* __restrict__ perm_dst, const float* __restrict__ ea,
                             const float* __restrict__ Mf, const float* __restrict__ als,
                             const float* __restrict__ ald, float* __restrict__ alpha, int E){
  __shared__ float Ms[48];
  if (threadIdx.x < 6*HH) Ms[threadIdx.x] = Mf[threadIdx.x];
  __syncthreads();
  int i = blockIdx.x*256 + threadIdx.x;
  if (i >= E) return;
  int e = perm_edge[i], s = perm_src[i], d = perm_dst[i];
  float eav[6];
#pragma unroll
  for (int k = 0; k < 6; ++k) eav[k] = ea[(size_t)e*6 + k];
#pragma unroll
  for (int h = 0; h < HH; ++h){
    float ale = 0.f;
#pragma unroll
    for (int k = 0; k < 6; ++k) ale += eav[k] * Ms[k*HH + h];
    float v = als[s*HH + h] + ald[d*HH + h] + ale;
    alpha[(size_t)i*HH + h] = (v > 0.f) ? v : NEG_SLOPE*v;
  }
}

// ===================== per-node softmax + weighted aggregation (1 wave / node) =====================
template<int HH>
__global__ void agg_kernel(const int* __restrict__ offs, const int* __restrict__ perm_src,
                           const float* __restrict__ alpha, const float* __restrict__ xp,
                           const float* __restrict__ bias, float* __restrict__ out,
                           int Nn, int do_relu){
  int gid = blockIdx.x*blockDim.x + threadIdx.x;
  int wave = gid >> 6, lane = threadIdx.x & 63;
  if (wave >= Nn) return;
  int beg = offs[wave], end = offs[wave+1];

  float mx[HH];
#pragma unroll
  for (int h = 0; h < HH; ++h) mx[h] = -3.0e38f;
  for (int i = beg + lane; i < end; i += 64){
    if constexpr (HH == 8){
      const float4* A4 = reinterpret_cast<const float4*>(alpha);
      float4 u = A4[2*(size_t)i], v = A4[2*(size_t)i + 1];
      mx[0]=fmaxf(mx[0],u.x); mx[1]=fmaxf(mx[1],u.y); mx[2]=fmaxf(mx[2],u.z); mx[3]=fmaxf(mx[3],u.w);
      mx[4]=fmaxf(mx[4],v.x); mx[5]=fmaxf(mx[5],v.y); mx[6]=fmaxf(mx[6],v.z); mx[7]=fmaxf(mx[7],v.w);
    } else {
      mx[0] = fmaxf(mx[0], alpha[i]);
    }
  }
#pragma unroll
  for (int off = 1; off < 64; off <<= 1)
#pragma unroll
    for (int h = 0; h < HH; ++h) mx[h] = fmaxf(mx[h], __shfl_xor(mx[h], off));

  float sm[HH];
#pragma unroll
  for (int h = 0; h < HH; ++h) sm[h] = 0.f;
  for (int i = beg + lane; i < end; i += 64){
    if constexpr (HH == 8){
      const float4* A4 = reinterpret_cast<const float4*>(alpha);
      float4 u = A4[2*(size_t)i], v = A4[2*(size_t)i + 1];
      sm[0]+=__expf(u.x-mx[0]); sm[1]+=__expf(u.y-mx[1]); sm[2]+=__expf(u.z-mx[2]); sm[3]+=__expf(u.w-mx[3]);
      sm[4]+=__expf(v.x-mx[4]); sm[5]+=__expf(v.y-mx[5]); sm[6]+=__expf(v.z-mx[6]); sm[7]+=__expf(v.w-mx[7]);
    } else {
      sm[0] += __expf(alpha[i]-mx[0]);
    }
  }
#pragma unroll
  for (int off = 1; off < 64; off <<= 1)
#pragma unroll
    for (int h = 0; h < HH; ++h) sm[h] += __shfl_xor(sm[h], off);

  float my_m, my_r;
  if constexpr (HH == 8){
    int h = lane >> 3;
    float rd[8];
#pragma unroll
    for (int j = 0; j < 8; ++j) rd[j] = 1.f/(sm[j] + 1e-16f);
    my_m = mx[0]; my_r = rd[0];
#pragma unroll
    for (int j = 1; j < 8; ++j){ if (h == j){ my_m = mx[j]; my_r = rd[j]; } }
  } else {
    my_m = mx[0]; my_r = 1.f/(sm[0] + 1e-16f);
  }

  float4 acc = make_float4(0.f,0.f,0.f,0.f);
  for (int i = beg; i < end; ++i){
    int s = perm_src[i];
    float a = (HH==8) ? alpha[(size_t)i*8 + (lane>>3)] : alpha[i];
    float w = __expf(a - my_m) * my_r;
    float4 xv = reinterpret_cast<const float4*>(xp)[(size_t)s*64 + lane];
    acc.x += xv.x*w; acc.y += xv.y*w; acc.z += xv.z*w; acc.w += xv.w*w;
  }
  float4 bv = reinterpret_cast<const float4*>(bias)[lane];
  acc.x += bv.x; acc.y += bv.y; acc.z += bv.z; acc.w += bv.w;
  if (do_relu){
    acc.x = fmaxf(acc.x,0.f); acc.y = fmaxf(acc.y,0.f);
    acc.z = fmaxf(acc.z,0.f); acc.w = fmaxf(acc.w,0.f);
  }
  reinterpret_cast<float4*>(out)[(size_t)wave*64 + lane] = acc;
}

// ===================== MLP path =====================
__global__ void h1_kernel(const float* __restrict__ nf, const float* __restrict__ w1,
                          const float* __restrict__ b1, const float* __restrict__ g,
                          const float* __restrict__ be, float* __restrict__ out){
  int b = blockIdx.x, j = threadIdx.x;   // 256 threads
  float s = b1[j];
#pragma unroll
  for (int k = 0; k < 10; ++k) s += nf[b*10 + k] * w1[k*256 + j];
  s = g[j]*s*BN_INV + be[j];
  out[b*256 + j] = fmaxf(s, 0.f);
}

__global__ void gather_kernel(const int* __restrict__ ids, const float* __restrict__ gat3out,
                              const float* __restrict__ netemb, float* __restrict__ comb){
  int b = blockIdx.x, t = threadIdx.x;   // 128 threads, float4 each
  float4 v;
  if (t < 64) v = reinterpret_cast<const float4*>(gat3out)[(size_t)ids[b]*64 + t];
  else        v = reinterpret_cast<const float4*>(netemb)[(size_t)b*64 + (t-64)];
  reinterpret_cast<float4*>(comb)[(size_t)b*128 + t] = v;
}

// ===================== host =====================
extern "C" void kernel_launch(void* const* d_in, const int* in_sizes, int n_in,
                              void* d_out, int out_size, void* d_ws, size_t ws_size,
                              hipStream_t stream)
{
  const int*   ids   = (const int*)  d_in[0];
  const float* nf    = (const float*)d_in[1];
  const int*   eidx  = (const int*)  d_in[2];
  const float* eattr = (const float*)d_in[3];
  const float* emb   = (const float*)d_in[4];
  const float* w1    = (const float*)d_in[5];
  const float* b1    = (const float*)d_in[6];
  const float* g1    = (const float*)d_in[7];
  const float* be1   = (const float*)d_in[8];
  const float* w2    = (const float*)d_in[9];
  const float* b2    = (const float*)d_in[10];
  const float* g2    = (const float*)d_in[11];
  const float* be2   = (const float*)d_in[12];
  const float* gW[3]  = {(const float*)d_in[13], (const float*)d_in[19], (const float*)d_in[25]};
  const float* gas[3] = {(const float*)d_in[14], (const float*)d_in[20], (const float*)d_in[26]};
  const float* gad[3] = {(const float*)d_in[15], (const float*)d_in[21], (const float*)d_in[27]};
  const float* gWe[3] = {(const float*)d_in[16], (const float*)d_in[22], (const float*)d_in[28]};
  const float* gae[3] = {(const float*)d_in[17], (const float*)d_in[23], (const float*)d_in[29]};
  const float* gb[3]  = {(const float*)d_in[18], (const float*)d_in[24], (const float*)d_in[30]};
  const float* fus_w  = (const float*)d_in[31];
  const float* fus_b  = (const float*)d_in[32];
  const float* fus_g  = (const float*)d_in[33];
  const float* fus_be = (const float*)d_in[34];
  const float* cls_w  = (const float*)d_in[35];
  const float* cls_b  = (const float*)d_in[36];

  const int E  = in_sizes[3] / 6;     // 320000
  const int Nn = in_sizes[4] / 256;   // 20000
  const int B  = in_sizes[0];         // 2048
  const int Ncls = in_sizes[36];      // 20000
  const int* src = eidx;
  const int* dst = eidx + E;

  // workspace carve (256B-aligned chunks)
  char* wbase = (char*)d_ws;
  size_t woff = 0;
  auto carve = [&](size_t bytes)->void*{
    void* p = wbase + woff;
    woff = (woff + bytes + 255) & ~(size_t)255;
    return p;
  };
  int*   offs      = (int*)  carve((size_t)(Nn+1)*4);
  int*   cursor    = (int*)  carve((size_t)Nn*4);
  int*   perm_edge = (int*)  carve((size_t)E*4);
  int*   perm_src  = (int*)  carve((size_t)E*4);
  int*   perm_dst  = (int*)  carve((size_t)E*4);
  float* bufA      = (float*)carve((size_t)Nn*256*4);   // xp
  float* bufB      = (float*)carve((size_t)Nn*256*4);   // out1 / out3
  float* bufC      = (float*)carve((size_t)Nn*256*4);   // out2
  float* als       = (float*)carve((size_t)Nn*8*4);
  float* ald       = (float*)carve((size_t)Nn*8*4);
  float* alpha     = (float*)carve((size_t)E*8*4);
  float* Mfold     = (float*)carve(64*4);
  float* h1b       = (float*)carve((size_t)B*256*4);
  float* netemb    = (float*)carve((size_t)B*256*4);
  float* comb      = (float*)carve((size_t)B*512*4);
  float* fused     = (float*)carve((size_t)B*256*4);
  (void)ws_size; (void)n_in; (void)out_size;

  // ---- CSR build (dst fixed across layers) ----
  hipMemsetAsync(cursor, 0, (size_t)Nn*4, stream);
  hist_kernel<<<(E+255)/256, 256, 0, stream>>>(dst, cursor, E);
  scan_kernel<<<1, 1024, 0, stream>>>(cursor, offs, Nn);
  scatter_kernel<<<(E+255)/256, 256, 0, stream>>>(src, dst, cursor, perm_edge, perm_src, perm_dst, E);

  // ---- 3 GAT layers ----
  const float* inx[3]  = {emb, bufB, bufC};
  float*       outx[3] = {bufB, bufC, bufB};
  const int    Hs[3]   = {8, 8, 1};
  dim3 gemm_grid_xp(4, (Nn+63)/64);
  int node_blocks = (Nn*64 + 255)/256;
  for (int l = 0; l < 3; ++l){
    foldm_kernel<<<1, 64, 0, stream>>>(gWe[l], gae[l], Mfold, Hs[l]);
    gemm_kernel<false,false,false><<<gemm_grid_xp, 256, 0, stream>>>(
        inx[l], gW[l], nullptr, nullptr, nullptr, bufA, Nn, 256, 256);
    if (Hs[l] == 8){
      alsd_kernel<8><<<node_blocks, 256, 0, stream>>>(bufA, gas[l], gad[l], als, ald, Nn);
      alpha_kernel<8><<<(E+255)/256, 256, 0, stream>>>(perm_edge, perm_src, perm_dst, eattr,
                                                       Mfold, als, ald, alpha, E);
      agg_kernel<8><<<node_blocks, 256, 0, stream>>>(offs, perm_src, alpha, bufA, gb[l],
                                                     outx[l], Nn, (l < 2) ? 1 : 0);
    } else {
      alsd_kernel<1><<<node_blocks, 256, 0, stream>>>(bufA, gas[l], gad[l], als, ald, Nn);
      alpha_kernel<1><<<(E+255)/256, 256, 0, stream>>>(perm_edge, perm_src, perm_dst, eattr,
                                                       Mfold, als, ald, alpha, E);
      agg_kernel<1><<<node_blocks, 256, 0, stream>>>(offs, perm_src, alpha, bufA, gb[l],
                                                     outx[l], Nn, 0);
    }
  }

  // ---- MLP path ----
  h1_kernel<<<B, 256, 0, stream>>>(nf, w1, b1, g1, be1, h1b);
  gemm_kernel<true,true,true><<<dim3(4, B/64), 256, 0, stream>>>(
      h1b, w2, b2, g2, be2, netemb, B, 256, 256);

  // ---- fuse + classify ----
  gather_kernel<<<B, 128, 0, stream>>>(ids, bufB, netemb, comb);
  gemm_kernel<true,true,true><<<dim3(4, B/64), 256, 0, stream>>>(
      comb, fus_w, fus_b, fus_g, fus_be, fused, B, 256, 512);
  gemm_kernel<true,false,false><<<dim3((Ncls+63)/64, B/64), 256, 0, stream>>>(
      fused, cls_w, cls_b, nullptr, nullptr, (float*)d_out, B, Ncls, 256);
}

// Round 2
// 930.260 us; speedup vs baseline: 1.2565x; 1.2565x over previous
//
#include <hip/hip_runtime.h>

#define NEG_SLOPE 0.2f
static constexpr float BN_INV = 0.9999950000374997f; // 1/sqrt(1+1e-5)

typedef __bf16 bf16x8 __attribute__((ext_vector_type(8)));
typedef float  f32x4  __attribute__((ext_vector_type(4)));

// ===================== CSR build =====================
__global__ void hist_kernel(const int* __restrict__ dst, int* __restrict__ cnt, int E){
  int e = blockIdx.x*256 + threadIdx.x;
  if (e < E) atomicAdd(&cnt[dst[e]], 1);
}

__global__ __launch_bounds__(1024) void scan_kernel(int* __restrict__ cnt_cursor, int* __restrict__ offs, int n){
  __shared__ int sdata[1024];
  __shared__ int carry;
  int tid = threadIdx.x;
  if (tid == 0){ carry = 0; offs[0] = 0; }
  __syncthreads();
  for (int base = 0; base < n; base += 1024){
    int i = base + tid;
    int v = (i < n) ? cnt_cursor[i] : 0;
    sdata[tid] = v;
    __syncthreads();
    for (int off = 1; off < 1024; off <<= 1){
      int t = (tid >= off) ? sdata[tid - off] : 0;
      __syncthreads();
      sdata[tid] += t;
      __syncthreads();
    }
    int inc = sdata[tid] + carry;    // inclusive prefix
    if (i < n){ offs[i+1] = inc; cnt_cursor[i] = inc - v; }  // cursor = exclusive start
    __syncthreads();
    if (tid == 1023) carry = inc;
    __syncthreads();
  }
}

__global__ void scatter_kernel(const int* __restrict__ src, const int* __restrict__ dst,
                               int* __restrict__ cursor, int* __restrict__ perm_edge,
                               int* __restrict__ perm_src, int* __restrict__ perm_dst, int E){
  int e = blockIdx.x*256 + threadIdx.x;
  if (e >= E) return;
  int d = dst[e];
  int pos = atomicAdd(&cursor[d], 1);
  perm_edge[pos] = e;
  perm_src[pos]  = src[e];
  perm_dst[pos]  = d;
}

// ===================== fold We @ ae -> M[6][H] =====================
__global__ void foldm_kernel(const float* __restrict__ We, const float* __restrict__ ae,
                             float* __restrict__ M, int H){
  int t = threadIdx.x;
  if (t >= 6*H) return;
  int C = 256 / H;
  int k = t / H, h = t % H;
  float s = 0.f;
  for (int c = 0; c < C; ++c) s += We[k*256 + h*C + c] * ae[h*C + c];
  M[k*H + h] = s;
}

// ===================== generic fp32 GEMM: C = act(bn(A@W + bias)) =====================
template<bool USE_BIAS, bool USE_BN, bool USE_RELU, typename OutT>
__global__ __launch_bounds__(256) void gemm_kernel(
    const float* __restrict__ A, const float* __restrict__ W,
    const float* __restrict__ bias, const float* __restrict__ gam, const float* __restrict__ bet,
    OutT* __restrict__ C, int M, int N, int K)
{
  __shared__ float As[32][68];
  __shared__ float Bs[32][64];
  int tid = threadIdx.x;
  int tx = tid & 15, ty = tid >> 4;
  int bn0 = blockIdx.x * 64, bm0 = blockIdx.y * 64;
  float acc[4][4] = {};
  for (int k0 = 0; k0 < K; k0 += 32){
    int kk = tid & 31, mm0 = tid >> 5;
#pragma unroll
    for (int r = 0; r < 8; ++r){
      int ml = mm0 + r*8;
      int m = bm0 + ml;
      As[kk][ml] = (m < M) ? A[(size_t)m*K + k0 + kk] : 0.f;
    }
    int nn = tid & 63, kb = tid >> 6;
#pragma unroll
    for (int r = 0; r < 8; ++r){
      int kl = kb + r*4;
      int n = bn0 + nn;
      Bs[kl][nn] = (n < N) ? W[(size_t)(k0 + kl)*N + n] : 0.f;
    }
    __syncthreads();
#pragma unroll
    for (int k = 0; k < 32; ++k){
      float4 a4 = *reinterpret_cast<const float4*>(&As[k][ty*4]);
      float4 b4 = *reinterpret_cast<const float4*>(&Bs[k][tx*4]);
      acc[0][0] += a4.x*b4.x; acc[0][1] += a4.x*b4.y; acc[0][2] += a4.x*b4.z; acc[0][3] += a4.x*b4.w;
      acc[1][0] += a4.y*b4.x; acc[1][1] += a4.y*b4.y; acc[1][2] += a4.y*b4.z; acc[1][3] += a4.y*b4.w;
      acc[2][0] += a4.z*b4.x; acc[2][1] += a4.z*b4.y; acc[2][2] += a4.z*b4.z; acc[2][3] += a4.z*b4.w;
      acc[3][0] += a4.w*b4.x; acc[3][1] += a4.w*b4.y; acc[3][2] += a4.w*b4.z; acc[3][3] += a4.w*b4.w;
    }
    __syncthreads();
  }
#pragma unroll
  for (int i = 0; i < 4; ++i){
    int m = bm0 + ty*4 + i;
    if (m < M){
#pragma unroll
      for (int j = 0; j < 4; ++j){
        int n = bn0 + tx*4 + j;
        if (n < N){
          float c = acc[i][j];
          if (USE_BIAS) c += bias[n];
          if (USE_BN)   c = gam[n]*c*BN_INV + bet[n];
          if (USE_RELU) c = fmaxf(c, 0.f);
          C[(size_t)m*N + n] = (OutT)c;
        }
      }
    }
  }
}

// ===================== transpose+convert cls_w [K,N] f32 -> [N,K] bf16 =====================
__global__ void wtrans_kernel(const float* __restrict__ W, __bf16* __restrict__ Wt, int K, int N){
  __shared__ float tile[32][33];
  int n0 = blockIdx.x*32, k0 = blockIdx.y*32;
  int t = threadIdx.x;                // 256 threads
  int nl = t & 31, kl = t >> 5;       // kl 0..7
#pragma unroll
  for (int r = 0; r < 4; ++r)
    tile[kl + r*8][nl] = W[(size_t)(k0 + kl + r*8)*N + n0 + nl];
  __syncthreads();
  int nl2 = t >> 3, kc = (t & 7)*4;
#pragma unroll
  for (int j = 0; j < 4; ++j)
    Wt[(size_t)(n0 + nl2)*K + k0 + kc + j] = (__bf16)tile[kc + j][nl2];
}

// ===================== bf16 MFMA GEMM: C[M,N] = A[M,K] * Bt[N,K]^T + bias =====================
// BM=128, BN=128, BK=64; 256 thr = 4 waves (2x2), each wave 64x64 via 4x4 mfma_16x16x32
__global__ __launch_bounds__(256) void cls_gemm_kernel(
    const __bf16* __restrict__ A, const __bf16* __restrict__ Bt,
    const float* __restrict__ bias, float* __restrict__ C, int M, int N, int K)
{
  __shared__ __bf16 As[128*72];   // row stride 72 elems (144 B): quad rows spread banks, 2-way free
  __shared__ __bf16 Bs[128*72];
  int tid = threadIdx.x;
  int lane = tid & 63, w = tid >> 6;
  int quad = lane >> 4, l16 = lane & 15;
  int wm = (w & 1) * 64, wn = (w >> 1) * 64;
  int bn0 = blockIdx.x * 128, bm0 = blockIdx.y * 128;
  f32x4 acc[4][4] = {};
  for (int k0 = 0; k0 < K; k0 += 64){
#pragma unroll
    for (int p = 0; p < 4; ++p){
      int idx = p*256 + tid;
      int row = idx >> 3, ch = idx & 7;
      uint4 av = *reinterpret_cast<const uint4*>(&A[(size_t)(bm0 + row)*K + k0 + ch*8]);
      *reinterpret_cast<uint4*>(&As[row*72 + ch*8]) = av;
      int n = bn0 + row;
      uint4 bv = make_uint4(0,0,0,0);
      if (n < N) bv = *reinterpret_cast<const uint4*>(&Bt[(size_t)n*K + k0 + ch*8]);
      *reinterpret_cast<uint4*>(&Bs[row*72 + ch*8]) = bv;
    }
    __syncthreads();
#pragma unroll
    for (int s = 0; s < 2; ++s){
      bf16x8 af[4], bfr[4];
#pragma unroll
      for (int t4 = 0; t4 < 4; ++t4){
        af[t4]  = *reinterpret_cast<const bf16x8*>(&As[(wm + t4*16 + l16)*72 + s*32 + quad*8]);
        bfr[t4] = *reinterpret_cast<const bf16x8*>(&Bs[(wn + t4*16 + l16)*72 + s*32 + quad*8]);
      }
#pragma unroll
      for (int mt = 0; mt < 4; ++mt)
#pragma unroll
        for (int nt = 0; nt < 4; ++nt)
          acc[mt][nt] = __builtin_amdgcn_mfma_f32_16x16x32_bf16(af[mt], bfr[nt], acc[mt][nt], 0, 0, 0);
    }
    __syncthreads();
  }
  // C/D layout: col = lane&15, row = quad*4 + reg  [m89-verified]
#pragma unroll
  for (int mt = 0; mt < 4; ++mt){
#pragma unroll
    for (int nt = 0; nt < 4; ++nt){
      int n = bn0 + wn + nt*16 + l16;
      if (n < N){
        float bv = bias[n];
#pragma unroll
        for (int r = 0; r < 4; ++r){
          int m = bm0 + wm + mt*16 + quad*4 + r;
          C[(size_t)m*N + n] = acc[mt][nt][r] + bv;
        }
      }
    }
  }
}

// ===================== per-node attention logits al_s/al_d =====================
template<int HH>
__global__ void alsd_kernel(const float* __restrict__ xp, const float* __restrict__ a_s,
                            const float* __restrict__ a_d, float* __restrict__ als,
                            float* __restrict__ ald, int Nn){
  int gid = blockIdx.x*blockDim.x + threadIdx.x;
  int wave = gid >> 6, lane = threadIdx.x & 63;
  if (wave >= Nn) return;
  float4 xv = reinterpret_cast<const float4*>(xp)[(size_t)wave*64 + lane];
  float4 av = reinterpret_cast<const float4*>(a_s)[lane];
  float4 dv = reinterpret_cast<const float4*>(a_d)[lane];
  float ps = xv.x*av.x + xv.y*av.y + xv.z*av.z + xv.w*av.w;
  float pd = xv.x*dv.x + xv.y*dv.y + xv.z*dv.z + xv.w*dv.w;
  if constexpr (HH == 8){
    ps += __shfl_xor(ps,1); pd += __shfl_xor(pd,1);
    ps += __shfl_xor(ps,2); pd += __shfl_xor(pd,2);
    ps += __shfl_xor(ps,4); pd += __shfl_xor(pd,4);
    if ((lane & 7) == 0){
      als[wave*8 + (lane>>3)] = ps;
      ald[wave*8 + (lane>>3)] = pd;
    }
  } else {
#pragma unroll
    for (int off = 1; off < 64; off <<= 1){ ps += __shfl_xor(ps,off); pd += __shfl_xor(pd,off); }
    if (lane == 0){ als[wave] = ps; ald[wave] = pd; }
  }
}

// ===================== per-edge attention logits (sorted order) =====================
template<int HH>
__global__ void alpha_kernel(const int* __restrict__ perm_edge, const int* __restrict__ perm_src,
                             const int* __restrict__ perm_dst, const float* __restrict__ ea,
                             const float* __restrict__ Mf, const float* __restrict__ als,
                             const float* __restrict__ ald, float* __restrict__ alpha, int E){
  __shared__ float Ms[48];
  if (threadIdx.x < 6*HH) Ms[threadIdx.x] = Mf[threadIdx.x];
  __syncthreads();
  int i = blockIdx.x*256 + threadIdx.x;
  if (i >= E) return;
  int e = perm_edge[i], s = perm_src[i], d = perm_dst[i];
  float eav[6];
#pragma unroll
  for (int k = 0; k < 6; ++k) eav[k] = ea[(size_t)e*6 + k];
#pragma unroll
  for (int h = 0; h < HH; ++h){
    float ale = 0.f;
#pragma unroll
    for (int k = 0; k < 6; ++k) ale += eav[k] * Ms[k*HH + h];
    float v = als[s*HH + h] + ald[d*HH + h] + ale;
    alpha[(size_t)i*HH + h] = (v > 0.f) ? v : NEG_SLOPE*v;
  }
}

// ===================== per-node softmax + weighted aggregation (1 wave / node) =====================
template<int HH>
__global__ void agg_kernel(const int* __restrict__ offs, const int* __restrict__ perm_src,
                           const float* __restrict__ alpha, const float* __restrict__ xp,
                           const float* __restrict__ bias, float* __restrict__ out,
                           int Nn, int do_relu){
  int gid = blockIdx.x*blockDim.x + threadIdx.x;
  int wave = gid >> 6, lane = threadIdx.x & 63;
  if (wave >= Nn) return;
  int beg = offs[wave], end = offs[wave+1];

  float mx[HH];
#pragma unroll
  for (int h = 0; h < HH; ++h) mx[h] = -3.0e38f;
  for (int i = beg + lane; i < end; i += 64){
    if constexpr (HH == 8){
      const float4* A4 = reinterpret_cast<const float4*>(alpha);
      float4 u = A4[2*(size_t)i], v = A4[2*(size_t)i + 1];
      mx[0]=fmaxf(mx[0],u.x); mx[1]=fmaxf(mx[1],u.y); mx[2]=fmaxf(mx[2],u.z); mx[3]=fmaxf(mx[3],u.w);
      mx[4]=fmaxf(mx[4],v.x); mx[5]=fmaxf(mx[5],v.y); mx[6]=fmaxf(mx[6],v.z); mx[7]=fmaxf(mx[7],v.w);
    } else {
      mx[0] = fmaxf(mx[0], alpha[i]);
    }
  }
#pragma unroll
  for (int off = 1; off < 64; off <<= 1)
#pragma unroll
    for (int h = 0; h < HH; ++h) mx[h] = fmaxf(mx[h], __shfl_xor(mx[h], off));

  float sm[HH];
#pragma unroll
  for (int h = 0; h < HH; ++h) sm[h] = 0.f;
  for (int i = beg + lane; i < end; i += 64){
    if constexpr (HH == 8){
      const float4* A4 = reinterpret_cast<const float4*>(alpha);
      float4 u = A4[2*(size_t)i], v = A4[2*(size_t)i + 1];
      sm[0]+=__expf(u.x-mx[0]); sm[1]+=__expf(u.y-mx[1]); sm[2]+=__expf(u.z-mx[2]); sm[3]+=__expf(u.w-mx[3]);
      sm[4]+=__expf(v.x-mx[4]); sm[5]+=__expf(v.y-mx[5]); sm[6]+=__expf(v.z-mx[6]); sm[7]+=__expf(v.w-mx[7]);
    } else {
      sm[0] += __expf(alpha[i]-mx[0]);
    }
  }
#pragma unroll
  for (int off = 1; off < 64; off <<= 1)
#pragma unroll
    for (int h = 0; h < HH; ++h) sm[h] += __shfl_xor(sm[h], off);

  float my_m, my_r;
  if constexpr (HH == 8){
    int h = lane >> 3;
    float rd[8];
#pragma unroll
    for (int j = 0; j < 8; ++j) rd[j] = 1.f/(sm[j] + 1e-16f);
    my_m = mx[0]; my_r = rd[0];
#pragma unroll
    for (int j = 1; j < 8; ++j){ if (h == j){ my_m = mx[j]; my_r = rd[j]; } }
  } else {
    my_m = mx[0]; my_r = 1.f/(sm[0] + 1e-16f);
  }

  float4 acc = make_float4(0.f,0.f,0.f,0.f);
  for (int i = beg; i < end; ++i){
    int s = perm_src[i];
    float a = (HH==8) ? alpha[(size_t)i*8 + (lane>>3)] : alpha[i];
    float w = __expf(a - my_m) * my_r;
    float4 xv = reinterpret_cast<const float4*>(xp)[(size_t)s*64 + lane];
    acc.x += xv.x*w; acc.y += xv.y*w; acc.z += xv.z*w; acc.w += xv.w*w;
  }
  float4 bv = reinterpret_cast<const float4*>(bias)[lane];
  acc.x += bv.x; acc.y += bv.y; acc.z += bv.z; acc.w += bv.w;
  if (do_relu){
    acc.x = fmaxf(acc.x,0.f); acc.y = fmaxf(acc.y,0.f);
    acc.z = fmaxf(acc.z,0.f); acc.w = fmaxf(acc.w,0.f);
  }
  reinterpret_cast<float4*>(out)[(size_t)wave*64 + lane] = acc;
}

// ===================== MLP path =====================
__global__ void h1_kernel(const float* __restrict__ nf, const float* __restrict__ w1,
                          const float* __restrict__ b1, const float* __restrict__ g,
                          const float* __restrict__ be, float* __restrict__ out){
  int b = blockIdx.x, j = threadIdx.x;   // 256 threads
  float s = b1[j];
#pragma unroll
  for (int k = 0; k < 10; ++k) s += nf[b*10 + k] * w1[k*256 + j];
  s = g[j]*s*BN_INV + be[j];
  out[b*256 + j] = fmaxf(s, 0.f);
}

__global__ void gather_kernel(const int* __restrict__ ids, const float* __restrict__ gat3out,
                              const float* __restrict__ netemb, float* __restrict__ comb){
  int b = blockIdx.x, t = threadIdx.x;   // 128 threads, float4 each
  float4 v;
  if (t < 64) v = reinterpret_cast<const float4*>(gat3out)[(size_t)ids[b]*64 + t];
  else        v = reinterpret_cast<const float4*>(netemb)[(size_t)b*64 + (t-64)];
  reinterpret_cast<float4*>(comb)[(size_t)b*128 + t] = v;
}

// ===================== host =====================
extern "C" void kernel_launch(void* const* d_in, const int* in_sizes, int n_in,
                              void* d_out, int out_size, void* d_ws, size_t ws_size,
                              hipStream_t stream)
{
  const int*   ids   = (const int*)  d_in[0];
  const float* nf    = (const float*)d_in[1];
  const int*   eidx  = (const int*)  d_in[2];
  const float* eattr = (const float*)d_in[3];
  const float* emb   = (const float*)d_in[4];
  const float* w1    = (const float*)d_in[5];
  const float* b1    = (const float*)d_in[6];
  const float* g1    = (const float*)d_in[7];
  const float* be1   = (const float*)d_in[8];
  const float* w2    = (const float*)d_in[9];
  const float* b2    = (const float*)d_in[10];
  const float* g2    = (const float*)d_in[11];
  const float* be2   = (const float*)d_in[12];
  const float* gW[3]  = {(const float*)d_in[13], (const float*)d_in[19], (const float*)d_in[25]};
  const float* gas[3] = {(const float*)d_in[14], (const float*)d_in[20], (const float*)d_in[26]};
  const float* gad[3] = {(const float*)d_in[15], (const float*)d_in[21], (const float*)d_in[27]};
  const float* gWe[3] = {(const float*)d_in[16], (const float*)d_in[22], (const float*)d_in[28]};
  const float* gae[3] = {(const float*)d_in[17], (const float*)d_in[23], (const float*)d_in[29]};
  const float* gb[3]  = {(const float*)d_in[18], (const float*)d_in[24], (const float*)d_in[30]};
  const float* fus_w  = (const float*)d_in[31];
  const float* fus_b  = (const float*)d_in[32];
  const float* fus_g  = (const float*)d_in[33];
  const float* fus_be = (const float*)d_in[34];
  const float* cls_w  = (const float*)d_in[35];
  const float* cls_b  = (const float*)d_in[36];

  const int E  = in_sizes[3] / 6;     // 320000
  const int Nn = in_sizes[4] / 256;   // 20000
  const int B  = in_sizes[0];         // 2048
  const int Ncls = in_sizes[36];      // 20000
  const int* src = eidx;
  const int* dst = eidx + E;

  char* wbase = (char*)d_ws;
  size_t woff = 0;
  auto carve = [&](size_t bytes)->void*{
    void* p = wbase + woff;
    woff = (woff + bytes + 255) & ~(size_t)255;
    return p;
  };
  int*   offs      = (int*)  carve((size_t)(Nn+1)*4);
  int*   cursor    = (int*)  carve((size_t)Nn*4);
  int*   perm_edge = (int*)  carve((size_t)E*4);
  int*   perm_src  = (int*)  carve((size_t)E*4);
  int*   perm_dst  = (int*)  carve((size_t)E*4);
  float* bufA      = (float*)carve((size_t)Nn*256*4);   // xp
  float* bufB      = (float*)carve((size_t)Nn*256*4);   // out1 / out3
  float* bufC      = (float*)carve((size_t)Nn*256*4);   // out2
  float* als       = (float*)carve((size_t)Nn*8*4);
  float* ald       = (float*)carve((size_t)Nn*8*4);
  float* alpha     = (float*)carve((size_t)E*8*4);
  float* Mfold     = (float*)carve(64*4);
  float* h1b       = (float*)carve((size_t)B*256*4);
  float* netemb    = (float*)carve((size_t)B*256*4);
  float* comb      = (float*)carve((size_t)B*512*4);
  __bf16* fusedb   = (__bf16*)carve((size_t)B*256*2);
  __bf16* clsWt    = (__bf16*)carve((size_t)Ncls*256*2);
  (void)ws_size; (void)n_in; (void)out_size;

  // ---- CSR build (dst fixed across layers) ----
  hipMemsetAsync(cursor, 0, (size_t)Nn*4, stream);
  hist_kernel<<<(E+255)/256, 256, 0, stream>>>(dst, cursor, E);
  scan_kernel<<<1, 1024, 0, stream>>>(cursor, offs, Nn);
  scatter_kernel<<<(E+255)/256, 256, 0, stream>>>(src, dst, cursor, perm_edge, perm_src, perm_dst, E);

  // ---- classifier weight transpose+convert (independent of GAT) ----
  wtrans_kernel<<<dim3(Ncls/32, 256/32), 256, 0, stream>>>(cls_w, clsWt, 256, Ncls);

  // ---- 3 GAT layers ----
  const float* inx[3]  = {emb, bufB, bufC};
  float*       outx[3] = {bufB, bufC, bufB};
  const int    Hs[3]   = {8, 8, 1};
  dim3 gemm_grid_xp(4, (Nn+63)/64);
  int node_blocks = (Nn*64 + 255)/256;
  for (int l = 0; l < 3; ++l){
    foldm_kernel<<<1, 64, 0, stream>>>(gWe[l], gae[l], Mfold, Hs[l]);
    gemm_kernel<false,false,false,float><<<gemm_grid_xp, 256, 0, stream>>>(
        inx[l], gW[l], nullptr, nullptr, nullptr, bufA, Nn, 256, 256);
    if (Hs[l] == 8){
      alsd_kernel<8><<<node_blocks, 256, 0, stream>>>(bufA, gas[l], gad[l], als, ald, Nn);
      alpha_kernel<8><<<(E+255)/256, 256, 0, stream>>>(perm_edge, perm_src, perm_dst, eattr,
                                                       Mfold, als, ald, alpha, E);
      agg_kernel<8><<<node_blocks, 256, 0, stream>>>(offs, perm_src, alpha, bufA, gb[l],
                                                     outx[l], Nn, (l < 2) ? 1 : 0);
    } else {
      alsd_kernel<1><<<node_blocks, 256, 0, stream>>>(bufA, gas[l], gad[l], als, ald, Nn);
      alpha_kernel<1><<<(E+255)/256, 256, 0, stream>>>(perm_edge, perm_src, perm_dst, eattr,
                                                       Mfold, als, ald, alpha, E);
      agg_kernel<1><<<node_blocks, 256, 0, stream>>>(offs, perm_src, alpha, bufA, gb[l],
                                                     outx[l], Nn, 0);
    }
  }

  // ---- MLP path ----
  h1_kernel<<<B, 256, 0, stream>>>(nf, w1, b1, g1, be1, h1b);
  gemm_kernel<true,true,true,float><<<dim3(4, B/64), 256, 0, stream>>>(
      h1b, w2, b2, g2, be2, netemb, B, 256, 256);

  // ---- fuse (bf16 out) + classify (bf16 MFMA) ----
  gather_kernel<<<B, 128, 0, stream>>>(ids, bufB, netemb, comb);
  gemm_kernel<true,true,true,__bf16><<<dim3(4, B/64), 256, 0, stream>>>(
      comb, fus_w, fus_b, fus_g, fus_be, fusedb, B, 256, 512);
  cls_gemm_kernel<<<dim3((Ncls+127)/128, B/128), 256, 0, stream>>>(
      fusedb, clsWt, cls_b, (float*)d_out, B, Ncls, 256);
}

// Round 3
// 731.713 us; speedup vs baseline: 1.5974x; 1.2713x over previous
//
#include <hip/hip_runtime.h>

#define NEG_SLOPE 0.2f
static constexpr float BN_INV = 0.9999950000374997f; // 1/sqrt(1+1e-5)

typedef __bf16 bf16x8 __attribute__((ext_vector_type(8)));
typedef float  f32x4  __attribute__((ext_vector_type(4)));

__device__ inline float4 bf4f(ushort4 u){
  float4 r;
  r.x = __uint_as_float((unsigned)u.x << 16);
  r.y = __uint_as_float((unsigned)u.y << 16);
  r.z = __uint_as_float((unsigned)u.z << 16);
  r.w = __uint_as_float((unsigned)u.w << 16);
  return r;
}
__device__ inline ushort4 f4bf(float4 v){
  ushort4 u;
  u.x = __builtin_bit_cast(unsigned short, (__bf16)v.x);
  u.y = __builtin_bit_cast(unsigned short, (__bf16)v.y);
  u.z = __builtin_bit_cast(unsigned short, (__bf16)v.z);
  u.w = __builtin_bit_cast(unsigned short, (__bf16)v.w);
  return u;
}

// ===================== CSR build =====================
__global__ void hist_kernel(const int* __restrict__ dst, int* __restrict__ cnt, int E){
  int e = blockIdx.x*256 + threadIdx.x;
  if (e < E) atomicAdd(&cnt[dst[e]], 1);
}

// shuffle-based single-block scan: 2 barriers per 1024-chunk
__global__ __launch_bounds__(1024) void scan_kernel(int* __restrict__ cnt_cursor, int* __restrict__ offs, int n){
  __shared__ int wsum[16];
  int tid = threadIdx.x, lane = tid & 63, wv = tid >> 6;
  if (tid == 0) offs[0] = 0;
  int carry = 0;
  for (int base = 0; base < n; base += 1024){
    int i = base + tid;
    int v = (i < n) ? cnt_cursor[i] : 0;
    int x = v;
#pragma unroll
    for (int off = 1; off < 64; off <<= 1){
      int t = __shfl_up(x, off);
      if (lane >= off) x += t;
    }
    if (lane == 63) wsum[wv] = x;
    __syncthreads();
    int y = (lane < 16) ? wsum[lane] : 0;
#pragma unroll
    for (int off = 1; off < 16; off <<= 1){
      int t = __shfl_up(y, off);
      if (lane >= off) y += t;
    }
    int excl  = (wv == 0) ? 0 : __shfl(y, wv - 1);
    int total = __shfl(y, 15);
    int inc = carry + excl + x;
    if (i < n){ offs[i+1] = inc; cnt_cursor[i] = inc - v; }
    carry += total;
    __syncthreads();   // protect wsum WAR for next chunk
  }
}

// scatter: permute src + edge_attr into CSR(dst) order
__global__ void scatter_kernel(const int* __restrict__ src, const int* __restrict__ dst,
                               const float* __restrict__ ea, int* __restrict__ cursor,
                               int* __restrict__ perm_src, int* __restrict__ perm_dst,
                               float* __restrict__ ea_perm, int E){
  int e = blockIdx.x*256 + threadIdx.x;
  if (e >= E) return;
  int d = dst[e];
  int pos = atomicAdd(&cursor[d], 1);
  perm_src[pos] = src[e];
  perm_dst[pos] = d;
#pragma unroll
  for (int k = 0; k < 6; ++k) ea_perm[(size_t)pos*6 + k] = ea[(size_t)e*6 + k];
}

// ===================== fold We @ ae for all 3 layers =====================
// M layout: [0..47]=L1 (6x8), [48..95]=L2 (6x8), [96..101]=L3 (6x1)
__global__ void foldm_all_kernel(const float* __restrict__ We1, const float* __restrict__ ae1,
                                 const float* __restrict__ We2, const float* __restrict__ ae2,
                                 const float* __restrict__ We3, const float* __restrict__ ae3,
                                 float* __restrict__ M){
  int t = threadIdx.x;   // 128
  if (t < 96){
    const float* We = (t < 48) ? We1 : We2;
    const float* ae = (t < 48) ? ae1 : ae2;
    int u = t % 48, k = u / 8, h = u % 8;
    float s = 0.f;
    for (int c = 0; c < 32; ++c) s += We[k*256 + h*32 + c] * ae[h*32 + c];
    M[t] = s;
  } else if (t < 102){
    int k = t - 96;
    float s = 0.f;
    for (int c = 0; c < 256; ++c) s += We3[k*256 + c] * ae3[c];
    M[t] = s;
  }
}

// ===================== generic fp32 GEMM (MLP path) =====================
template<bool USE_BIAS, bool USE_BN, bool USE_RELU, typename OutT>
__global__ __launch_bounds__(256) void gemm_kernel(
    const float* __restrict__ A, const float* __restrict__ W,
    const float* __restrict__ bias, const float* __restrict__ gam, const float* __restrict__ bet,
    OutT* __restrict__ C, int M, int N, int K)
{
  __shared__ float As[32][68];
  __shared__ float Bs[32][64];
  int tid = threadIdx.x;
  int tx = tid & 15, ty = tid >> 4;
  int bn0 = blockIdx.x * 64, bm0 = blockIdx.y * 64;
  float acc[4][4] = {};
  for (int k0 = 0; k0 < K; k0 += 32){
    int kk = tid & 31, mm0 = tid >> 5;
#pragma unroll
    for (int r = 0; r < 8; ++r){
      int ml = mm0 + r*8;
      int m = bm0 + ml;
      As[kk][ml] = (m < M) ? A[(size_t)m*K + k0 + kk] : 0.f;
    }
    int nn = tid & 63, kb = tid >> 6;
#pragma unroll
    for (int r = 0; r < 8; ++r){
      int kl = kb + r*4;
      int n = bn0 + nn;
      Bs[kl][nn] = (n < N) ? W[(size_t)(k0 + kl)*N + n] : 0.f;
    }
    __syncthreads();
#pragma unroll
    for (int k = 0; k < 32; ++k){
      float4 a4 = *reinterpret_cast<const float4*>(&As[k][ty*4]);
      float4 b4 = *reinterpret_cast<const float4*>(&Bs[k][tx*4]);
      acc[0][0] += a4.x*b4.x; acc[0][1] += a4.x*b4.y; acc[0][2] += a4.x*b4.z; acc[0][3] += a4.x*b4.w;
      acc[1][0] += a4.y*b4.x; acc[1][1] += a4.y*b4.y; acc[1][2] += a4.y*b4.z; acc[1][3] += a4.y*b4.w;
      acc[2][0] += a4.z*b4.x; acc[2][1] += a4.z*b4.y; acc[2][2] += a4.z*b4.z; acc[2][3] += a4.z*b4.w;
      acc[3][0] += a4.w*b4.x; acc[3][1] += a4.w*b4.y; acc[3][2] += a4.w*b4.z; acc[3][3] += a4.w*b4.w;
    }
    __syncthreads();
  }
#pragma unroll
  for (int i = 0; i < 4; ++i){
    int m = bm0 + ty*4 + i;
    if (m < M){
#pragma unroll
      for (int j = 0; j < 4; ++j){
        int n = bn0 + tx*4 + j;
        if (n < N){
          float c = acc[i][j];
          if (USE_BIAS) c += bias[n];
          if (USE_BN)   c = gam[n]*c*BN_INV + bet[n];
          if (USE_RELU) c = fmaxf(c, 0.f);
          C[(size_t)m*N + n] = (OutT)c;
        }
      }
    }
  }
}

// ===================== transpose+convert W [K,N] f32 -> [N,K] bf16 =====================
__global__ void wtrans_kernel(const float* __restrict__ W, __bf16* __restrict__ Wt, int K, int N){
  __shared__ float tile[32][33];
  int n0 = blockIdx.x*32, k0 = blockIdx.y*32;
  int t = threadIdx.x;
  int nl = t & 31, kl = t >> 5;
#pragma unroll
  for (int r = 0; r < 4; ++r)
    tile[kl + r*8][nl] = W[(size_t)(k0 + kl + r*8)*N + n0 + nl];
  __syncthreads();
  int nl2 = t >> 3, kc = (t & 7)*4;
#pragma unroll
  for (int j = 0; j < 4; ++j)
    Wt[(size_t)(n0 + nl2)*K + k0 + kc + j] = (__bf16)tile[kc + j][nl2];
}

__global__ void wtrans3_kernel(const float* __restrict__ W0, const float* __restrict__ W1,
                               const float* __restrict__ W2, __bf16* __restrict__ Wt){
  __shared__ float tile[32][33];
  const float* W = (blockIdx.z == 0) ? W0 : (blockIdx.z == 1) ? W1 : W2;
  __bf16* D = Wt + (size_t)blockIdx.z * 65536;
  int n0 = blockIdx.x*32, k0 = blockIdx.y*32;
  int t = threadIdx.x;
  int nl = t & 31, kl = t >> 5;
#pragma unroll
  for (int r = 0; r < 4; ++r)
    tile[kl + r*8][nl] = W[(size_t)(k0 + kl + r*8)*256 + n0 + nl];
  __syncthreads();
  int nl2 = t >> 3, kc = (t & 7)*4;
#pragma unroll
  for (int j = 0; j < 4; ++j)
    D[(size_t)(n0 + nl2)*256 + k0 + kc + j] = (__bf16)tile[kc + j][nl2];
}

// ===================== f32 -> bf16 convert =====================
__global__ void cvt_kernel(const float* __restrict__ in, __bf16* __restrict__ out, int n4){
  int i = blockIdx.x*256 + threadIdx.x;
  if (i >= n4) return;
  float4 v = reinterpret_cast<const float4*>(in)[i];
  reinterpret_cast<ushort4*>(out)[i] = f4bf(v);
}

// ===================== bf16 MFMA GEMM: C[M,N] = A[M,K] * Bt[N,K]^T (+bias) =====================
// BM=128, BN=128, BK=64; 256 thr = 4 waves (2x2), each wave 64x64 via 4x4 mfma_16x16x32
// A must be padded to a multiple of 128 rows (pad rows readable garbage).
template<bool USE_BIAS, typename OutT>
__global__ __launch_bounds__(256) void mfma_gemm_kernel(
    const __bf16* __restrict__ A, const __bf16* __restrict__ Bt,
    const float* __restrict__ bias, OutT* __restrict__ C, int M, int N, int K)
{
  __shared__ __bf16 As[128*72];
  __shared__ __bf16 Bs[128*72];
  int tid = threadIdx.x;
  int lane = tid & 63, w = tid >> 6;
  int quad = lane >> 4, l16 = lane & 15;
  int wm = (w & 1) * 64, wn = (w >> 1) * 64;
  int bn0 = blockIdx.x * 128, bm0 = blockIdx.y * 128;
  f32x4 acc[4][4] = {};
  for (int k0 = 0; k0 < K; k0 += 64){
#pragma unroll
    for (int p = 0; p < 4; ++p){
      int idx = p*256 + tid;
      int row = idx >> 3, ch = idx & 7;
      uint4 av = *reinterpret_cast<const uint4*>(&A[(size_t)(bm0 + row)*K + k0 + ch*8]);
      *reinterpret_cast<uint4*>(&As[row*72 + ch*8]) = av;
      int n = bn0 + row;
      uint4 bv = make_uint4(0,0,0,0);
      if (n < N) bv = *reinterpret_cast<const uint4*>(&Bt[(size_t)n*K + k0 + ch*8]);
      *reinterpret_cast<uint4*>(&Bs[row*72 + ch*8]) = bv;
    }
    __syncthreads();
#pragma unroll
    for (int s = 0; s < 2; ++s){
      bf16x8 af[4], bfr[4];
#pragma unroll
      for (int t4 = 0; t4 < 4; ++t4){
        af[t4]  = *reinterpret_cast<const bf16x8*>(&As[(wm + t4*16 + l16)*72 + s*32 + quad*8]);
        bfr[t4] = *reinterpret_cast<const bf16x8*>(&Bs[(wn + t4*16 + l16)*72 + s*32 + quad*8]);
      }
#pragma unroll
      for (int mt = 0; mt < 4; ++mt)
#pragma unroll
        for (int nt = 0; nt < 4; ++nt)
          acc[mt][nt] = __builtin_amdgcn_mfma_f32_16x16x32_bf16(af[mt], bfr[nt], acc[mt][nt], 0, 0, 0);
    }
    __syncthreads();
  }
  // C/D layout: col = lane&15, row = quad*4 + reg  [m89-verified]
#pragma unroll
  for (int mt = 0; mt < 4; ++mt){
#pragma unroll
    for (int nt = 0; nt < 4; ++nt){
      int n = bn0 + wn + nt*16 + l16;
      if (n < N){
        float bv = USE_BIAS ? bias[n] : 0.f;
#pragma unroll
        for (int r = 0; r < 4; ++r){
          int m = bm0 + wm + mt*16 + quad*4 + r;
          if (m < M) C[(size_t)m*N + n] = (OutT)(acc[mt][nt][r] + bv);
        }
      }
    }
  }
}

// ===================== per-node attention logits al_s/al_d (bf16 xp) =====================
template<int HH>
__global__ void alsd_kernel(const __bf16* __restrict__ xp, const float* __restrict__ a_s,
                            const float* __restrict__ a_d, float* __restrict__ als,
                            float* __restrict__ ald, int Nn){
  int gid = blockIdx.x*blockDim.x + threadIdx.x;
  int wave = gid >> 6, lane = threadIdx.x & 63;
  if (wave >= Nn) return;
  float4 xv = bf4f(reinterpret_cast<const ushort4*>(xp)[(size_t)wave*64 + lane]);
  float4 av = reinterpret_cast<const float4*>(a_s)[lane];
  float4 dv = reinterpret_cast<const float4*>(a_d)[lane];
  float ps = xv.x*av.x + xv.y*av.y + xv.z*av.z + xv.w*av.w;
  float pd = xv.x*dv.x + xv.y*dv.y + xv.z*dv.z + xv.w*dv.w;
  if constexpr (HH == 8){
    ps += __shfl_xor(ps,1); pd += __shfl_xor(pd,1);
    ps += __shfl_xor(ps,2); pd += __shfl_xor(pd,2);
    ps += __shfl_xor(ps,4); pd += __shfl_xor(pd,4);
    if ((lane & 7) == 0){
      als[wave*8 + (lane>>3)] = ps;
      ald[wave*8 + (lane>>3)] = pd;
    }
  } else {
#pragma unroll
    for (int off = 1; off < 64; off <<= 1){ ps += __shfl_xor(ps,off); pd += __shfl_xor(pd,off); }
    if (lane == 0){ als[wave] = ps; ald[wave] = pd; }
  }
}

// ===================== per-edge attention logits (CSR order, coalesced ea) =====================
template<int HH>
__global__ void alpha_kernel(const int* __restrict__ perm_src, const int* __restrict__ perm_dst,
                             const float* __restrict__ ea_perm, const float* __restrict__ Mf,
                             const float* __restrict__ als, const float* __restrict__ ald,
                             float* __restrict__ alpha, int E){
  __shared__ float Ms[48];
  if (threadIdx.x < 6*HH) Ms[threadIdx.x] = Mf[threadIdx.x];
  __syncthreads();
  int i = blockIdx.x*256 + threadIdx.x;
  if (i >= E) return;
  int s = perm_src[i], d = perm_dst[i];
  float eav[6];
#pragma unroll
  for (int k = 0; k < 6; ++k) eav[k] = ea_perm[(size_t)i*6 + k];
#pragma unroll
  for (int h = 0; h < HH; ++h){
    float ale = 0.f;
#pragma unroll
    for (int k = 0; k < 6; ++k) ale += eav[k] * Ms[k*HH + h];
    float v = als[s*HH + h] + ald[d*HH + h] + ale;
    alpha[(size_t)i*HH + h] = (v > 0.f) ? v : NEG_SLOPE*v;
  }
}

// ===================== per-node softmax + weighted aggregation (1 wave / node, bf16 xp) ==========
template<int HH>
__global__ void agg_kernel(const int* __restrict__ offs, const int* __restrict__ perm_src,
                           const float* __restrict__ alpha, const __bf16* __restrict__ xp,
                           const float* __restrict__ bias, __bf16* __restrict__ out,
                           int Nn, int do_relu){
  int gid = blockIdx.x*blockDim.x + threadIdx.x;
  int wave = gid >> 6, lane = threadIdx.x & 63;
  if (wave >= Nn) return;
  int beg = offs[wave], end = offs[wave+1];

  float mx[HH];
#pragma unroll
  for (int h = 0; h < HH; ++h) mx[h] = -3.0e38f;
  for (int i = beg + lane; i < end; i += 64){
    if constexpr (HH == 8){
      const float4* A4 = reinterpret_cast<const float4*>(alpha);
      float4 u = A4[2*(size_t)i], v = A4[2*(size_t)i + 1];
      mx[0]=fmaxf(mx[0],u.x); mx[1]=fmaxf(mx[1],u.y); mx[2]=fmaxf(mx[2],u.z); mx[3]=fmaxf(mx[3],u.w);
      mx[4]=fmaxf(mx[4],v.x); mx[5]=fmaxf(mx[5],v.y); mx[6]=fmaxf(mx[6],v.z); mx[7]=fmaxf(mx[7],v.w);
    } else {
      mx[0] = fmaxf(mx[0], alpha[i]);
    }
  }
#pragma unroll
  for (int off = 1; off < 64; off <<= 1)
#pragma unroll
    for (int h = 0; h < HH; ++h) mx[h] = fmaxf(mx[h], __shfl_xor(mx[h], off));

  float sm[HH];
#pragma unroll
  for (int h = 0; h < HH; ++h) sm[h] = 0.f;
  for (int i = beg + lane; i < end; i += 64){
    if constexpr (HH == 8){
      const float4* A4 = reinterpret_cast<const float4*>(alpha);
      float4 u = A4[2*(size_t)i], v = A4[2*(size_t)i + 1];
      sm[0]+=__expf(u.x-mx[0]); sm[1]+=__expf(u.y-mx[1]); sm[2]+=__expf(u.z-mx[2]); sm[3]+=__expf(u.w-mx[3]);
      sm[4]+=__expf(v.x-mx[4]); sm[5]+=__expf(v.y-mx[5]); sm[6]+=__expf(v.z-mx[6]); sm[7]+=__expf(v.w-mx[7]);
    } else {
      sm[0] += __expf(alpha[i]-mx[0]);
    }
  }
#pragma unroll
  for (int off = 1; off < 64; off <<= 1)
#pragma unroll
    for (int h = 0; h < HH; ++h) sm[h] += __shfl_xor(sm[h], off);

  float my_m, my_r;
  if constexpr (HH == 8){
    int h = lane >> 3;
    float rd[8];
#pragma unroll
    for (int j = 0; j < 8; ++j) rd[j] = 1.f/(sm[j] + 1e-16f);
    my_m = mx[0]; my_r = rd[0];
#pragma unroll
    for (int j = 1; j < 8; ++j){ if (h == j){ my_m = mx[j]; my_r = rd[j]; } }
  } else {
    my_m = mx[0]; my_r = 1.f/(sm[0] + 1e-16f);
  }

  const ushort4* X4 = reinterpret_cast<const ushort4*>(xp);
  int hsel = (HH == 8) ? (lane >> 3) : 0;
  float4 acc = make_float4(0.f,0.f,0.f,0.f);
  int i = beg;
  for (; i + 3 < end; i += 4){
    int s0 = perm_src[i], s1 = perm_src[i+1], s2 = perm_src[i+2], s3 = perm_src[i+3];
    float a0, a1, a2, a3;
    if constexpr (HH == 8){
      a0 = alpha[(size_t)i*8 + hsel];     a1 = alpha[(size_t)(i+1)*8 + hsel];
      a2 = alpha[(size_t)(i+2)*8 + hsel]; a3 = alpha[(size_t)(i+3)*8 + hsel];
    } else { a0 = alpha[i]; a1 = alpha[i+1]; a2 = alpha[i+2]; a3 = alpha[i+3]; }
    float w0 = __expf(a0 - my_m)*my_r, w1 = __expf(a1 - my_m)*my_r;
    float w2 = __expf(a2 - my_m)*my_r, w3 = __expf(a3 - my_m)*my_r;
    float4 x0 = bf4f(X4[(size_t)s0*64 + lane]);
    float4 x1 = bf4f(X4[(size_t)s1*64 + lane]);
    float4 x2 = bf4f(X4[(size_t)s2*64 + lane]);
    float4 x3 = bf4f(X4[(size_t)s3*64 + lane]);
    acc.x += x0.x*w0 + x1.x*w1 + x2.x*w2 + x3.x*w3;
    acc.y += x0.y*w0 + x1.y*w1 + x2.y*w2 + x3.y*w3;
    acc.z += x0.z*w0 + x1.z*w1 + x2.z*w2 + x3.z*w3;
    acc.w += x0.w*w0 + x1.w*w1 + x2.w*w2 + x3.w*w3;
  }
  for (; i < end; ++i){
    int s = perm_src[i];
    float a = (HH==8) ? alpha[(size_t)i*8 + hsel] : alpha[i];
    float w = __expf(a - my_m) * my_r;
    float4 xv = bf4f(X4[(size_t)s*64 + lane]);
    acc.x += xv.x*w; acc.y += xv.y*w; acc.z += xv.z*w; acc.w += xv.w*w;
  }
  float4 bv = reinterpret_cast<const float4*>(bias)[lane];
  acc.x += bv.x; acc.y += bv.y; acc.z += bv.z; acc.w += bv.w;
  if (do_relu){
    acc.x = fmaxf(acc.x,0.f); acc.y = fmaxf(acc.y,0.f);
    acc.z = fmaxf(acc.z,0.f); acc.w = fmaxf(acc.w,0.f);
  }
  reinterpret_cast<ushort4*>(out)[(size_t)wave*64 + lane] = f4bf(acc);
}

// ===================== MLP path =====================
__global__ void h1_kernel(const float* __restrict__ nf, const float* __restrict__ w1,
                          const float* __restrict__ b1, const float* __restrict__ g,
                          const float* __restrict__ be, float* __restrict__ out){
  int b = blockIdx.x, j = threadIdx.x;
  float s = b1[j];
#pragma unroll
  for (int k = 0; k < 10; ++k) s += nf[b*10 + k] * w1[k*256 + j];
  s = g[j]*s*BN_INV + be[j];
  out[b*256 + j] = fmaxf(s, 0.f);
}

__global__ void gather_kernel(const int* __restrict__ ids, const __bf16* __restrict__ gat3out,
                              const float* __restrict__ netemb, float* __restrict__ comb){
  int b = blockIdx.x, t = threadIdx.x;   // 128 threads, float4 each
  float4 v;
  if (t < 64) v = bf4f(reinterpret_cast<const ushort4*>(gat3out)[(size_t)ids[b]*64 + t]);
  else        v = reinterpret_cast<const float4*>(netemb)[(size_t)b*64 + (t-64)];
  reinterpret_cast<float4*>(comb)[(size_t)b*128 + t] = v;
}

// ===================== host =====================
extern "C" void kernel_launch(void* const* d_in, const int* in_sizes, int n_in,
                              void* d_out, int out_size, void* d_ws, size_t ws_size,
                              hipStream_t stream)
{
  const int*   ids   = (const int*)  d_in[0];
  const float* nf    = (const float*)d_in[1];
  const int*   eidx  = (const int*)  d_in[2];
  const float* eattr = (const float*)d_in[3];
  const float* emb   = (const float*)d_in[4];
  const float* w1    = (const float*)d_in[5];
  const float* b1    = (const float*)d_in[6];
  const float* g1    = (const float*)d_in[7];
  const float* be1   = (const float*)d_in[8];
  const float* w2    = (const float*)d_in[9];
  const float* b2    = (const float*)d_in[10];
  const float* g2    = (const float*)d_in[11];
  const float* be2   = (const float*)d_in[12];
  const float* gW[3]  = {(const float*)d_in[13], (const float*)d_in[19], (const float*)d_in[25]};
  const float* gas[3] = {(const float*)d_in[14], (const float*)d_in[20], (const float*)d_in[26]};
  const float* gad[3] = {(const float*)d_in[15], (const float*)d_in[21], (const float*)d_in[27]};
  const float* gWe[3] = {(const float*)d_in[16], (const float*)d_in[22], (const float*)d_in[28]};
  const float* gae[3] = {(const float*)d_in[17], (const float*)d_in[23], (const float*)d_in[29]};
  const float* gb[3]  = {(const float*)d_in[18], (const float*)d_in[24], (const float*)d_in[30]};
  const float* fus_w  = (const float*)d_in[31];
  const float* fus_b  = (const float*)d_in[32];
  const float* fus_g  = (const float*)d_in[33];
  const float* fus_be = (const float*)d_in[34];
  const float* cls_w  = (const float*)d_in[35];
  const float* cls_b  = (const float*)d_in[36];

  const int E  = in_sizes[3] / 6;     // 320000
  const int Nn = in_sizes[4] / 256;   // 20000
  const int B  = in_sizes[0];         // 2048
  const int Ncls = in_sizes[36];      // 20000
  const int Npad = (Nn + 127) & ~127; // 20096
  const int* src = eidx;
  const int* dst = eidx + E;

  char* wbase = (char*)d_ws;
  size_t woff = 0;
  auto carve = [&](size_t bytes)->void*{
    void* p = wbase + woff;
    woff = (woff + bytes + 255) & ~(size_t)255;
    return p;
  };
  int*    offs     = (int*)   carve((size_t)(Nn+1)*4);
  int*    cursor   = (int*)   carve((size_t)Nn*4);
  int*    perm_src = (int*)   carve((size_t)E*4);
  int*    perm_dst = (int*)   carve((size_t)E*4);
  float*  ea_perm  = (float*) carve((size_t)E*6*4);
  __bf16* xb0      = (__bf16*)carve((size_t)Npad*256*2);
  __bf16* xb1      = (__bf16*)carve((size_t)Npad*256*2);
  __bf16* xpb      = (__bf16*)carve((size_t)Npad*256*2);
  __bf16* gWt      = (__bf16*)carve((size_t)3*256*256*2);
  float*  als      = (float*) carve((size_t)Nn*8*4);
  float*  ald      = (float*) carve((size_t)Nn*8*4);
  float*  alpha    = (float*) carve((size_t)E*8*4);
  float*  Mfold    = (float*) carve(128*4);
  float*  h1b      = (float*) carve((size_t)B*256*4);
  float*  netemb   = (float*) carve((size_t)B*256*4);
  float*  comb     = (float*) carve((size_t)B*512*4);
  __bf16* fusedb   = (__bf16*)carve((size_t)B*256*2);
  __bf16* clsWt    = (__bf16*)carve((size_t)Ncls*256*2);
  (void)ws_size; (void)n_in; (void)out_size;

  // ---- CSR build (dst fixed across layers) ----
  hipMemsetAsync(cursor, 0, (size_t)Nn*4, stream);
  hist_kernel<<<(E+255)/256, 256, 0, stream>>>(dst, cursor, E);
  scan_kernel<<<1, 1024, 0, stream>>>(cursor, offs, Nn);
  scatter_kernel<<<(E+255)/256, 256, 0, stream>>>(src, dst, eattr, cursor,
                                                  perm_src, perm_dst, ea_perm, E);

  // ---- weight prep + input convert ----
  foldm_all_kernel<<<1, 128, 0, stream>>>(gWe[0], gae[0], gWe[1], gae[1], gWe[2], gae[2], Mfold);
  wtrans3_kernel<<<dim3(8, 8, 3), 256, 0, stream>>>(gW[0], gW[1], gW[2], gWt);
  wtrans_kernel<<<dim3(Ncls/32, 256/32), 256, 0, stream>>>(cls_w, clsWt, 256, Ncls);
  cvt_kernel<<<(Nn*64 + 255)/256, 256, 0, stream>>>(emb, xb0, Nn*64);

  // ---- 3 GAT layers (all-bf16 feature path) ----
  const __bf16* inx[3]  = {xb0, xb1, xb0};
  __bf16*       outx[3] = {xb1, xb0, xb1};
  const int     Hs[3]   = {8, 8, 1};
  dim3 mfma_grid_xp(2, Npad/128);
  int node_blocks = (Nn*64 + 255)/256;
  for (int l = 0; l < 3; ++l){
    mfma_gemm_kernel<false, __bf16><<<mfma_grid_xp, 256, 0, stream>>>(
        inx[l], gWt + (size_t)l*65536, nullptr, xpb, Nn, 256, 256);
    const float* Mf = Mfold + (l == 2 ? 96 : l*48);
    if (Hs[l] == 8){
      alsd_kernel<8><<<node_blocks, 256, 0, stream>>>(xpb, gas[l], gad[l], als, ald, Nn);
      alpha_kernel<8><<<(E+255)/256, 256, 0, stream>>>(perm_src, perm_dst, ea_perm,
                                                       Mf, als, ald, alpha, E);
      agg_kernel<8><<<node_blocks, 256, 0, stream>>>(offs, perm_src, alpha, xpb, gb[l],
                                                     outx[l], Nn, (l < 2) ? 1 : 0);
    } else {
      alsd_kernel<1><<<node_blocks, 256, 0, stream>>>(xpb, gas[l], gad[l], als, ald, Nn);
      alpha_kernel<1><<<(E+255)/256, 256, 0, stream>>>(perm_src, perm_dst, ea_perm,
                                                       Mf, als, ald, alpha, E);
      agg_kernel<1><<<node_blocks, 256, 0, stream>>>(offs, perm_src, alpha, xpb, gb[l],
                                                     outx[l], Nn, 0);
    }
  }

  // ---- MLP path ----
  h1_kernel<<<B, 256, 0, stream>>>(nf, w1, b1, g1, be1, h1b);
  gemm_kernel<true,true,true,float><<<dim3(4, B/64), 256, 0, stream>>>(
      h1b, w2, b2, g2, be2, netemb, B, 256, 256);

  // ---- fuse (bf16 out) + classify (bf16 MFMA) ----
  gather_kernel<<<B, 128, 0, stream>>>(ids, xb1, netemb, comb);
  gemm_kernel<true,true,true,__bf16><<<dim3(4, B/64), 256, 0, stream>>>(
      comb, fus_w, fus_b, fus_g, fus_be, fusedb, B, 256, 512);
  mfma_gemm_kernel<true, float><<<dim3((Ncls+127)/128, B/128), 256, 0, stream>>>(
      fusedb, clsWt, cls_b, (float*)d_out, B, Ncls, 256);
}